// Round 15
// baseline (256.858 us; speedup 1.0000x reference)
//
#include <hip/hip_runtime.h>

typedef _Float16 f16x8  __attribute__((ext_vector_type(8)));
typedef _Float16 f16x4  __attribute__((ext_vector_type(4)));
typedef _Float16 f16x2  __attribute__((ext_vector_type(2)));
typedef float    f32x4  __attribute__((ext_vector_type(4)));
typedef float    f32x16 __attribute__((ext_vector_type(16)));
typedef int      i32x2  __attribute__((ext_vector_type(2)));

#define MFMA32(a, b, c) __builtin_amdgcn_mfma_f32_32x32x16_f16((a), (b), (c), 0, 0, 0)

static constexpr int SEQ   = 2048;
static constexpr int DIM   = 128;
static constexpr int QBLK  = 128;          // 4 waves x 32 q-rows
static constexpr int KVBLK = 32;           // kv rows per tile
static constexpr int NKT   = SEQ / KVBLK;  // 64
static constexpr int BH    = 2 * 16;
static constexpr int KSTR  = 136;          // K LDS row stride (f16), 272B padded
static constexpr int VSTR  = 40;           // Vt LDS row stride (f16), 80B padded

// o = exp(QK^T - rowmax) @ V  (unnormalized, fp32 in/out)
// r14 core (dbuf LDS, 1 barrier/iter, pinned prefetch, permlane PV, spec-P)
// + OPTIONAL k-split x2 across blocks (split=1): each half writes a partial O
// (own-max-corrected) + per-row max; fa_merge combines. Grid 1024 -> 3 blocks/CU
// resident (reg-capped 3 waves/SIMD) = 1.5x TLP vs the 512-block grid.
__global__ __launch_bounds__(256, 3)
void fa_fwd_kernel(const float* __restrict__ Qg, const float* __restrict__ Kg,
                   const float* __restrict__ Vg, float* __restrict__ OutA,
                   float* __restrict__ OutB, float* __restrict__ Mbase, int split)
{
    __shared__ __align__(16) _Float16 Ksh[2][KVBLK * KSTR];
    __shared__ __align__(16) _Float16 Vt[2][DIM * VSTR];

    const int tid  = threadIdx.x;
    const int wv   = tid >> 6;
    const int lane = tid & 63;
    const int lq   = lane & 31;   // q column (and K A-row) owned by this lane
    const int lh   = lane >> 5;   // half: 0/1

    // XCD swizzle: all blocks of one bh -> one XCD (K/V/Q L2-resident)
    const int bi = blockIdx.x;
    int bh, qt, khalf;
    if (split) { bh = (bi & 7) + 8 * (bi >> 8); khalf = (bi >> 3) & 1; qt = (bi >> 4) & 15; }
    else       { bh = (bi & 7) + 8 * (bi >> 7); khalf = 0;             qt = (bi >> 3) & 15; }
    const int nkt = split ? (NKT / 2) : NKT;

    const size_t base = (size_t)bh * SEQ * DIM;
    const float* Qp = Qg + base;
    const float* Kp = Kg + base + (size_t)khalf * (SEQ / 2) * DIM;
    const float* Vp = Vg + base + (size_t)khalf * (SEQ / 2) * DIM;
    float*       Op = (khalf ? OutB : OutA) + base;

    const int q0 = qt * QBLK + wv * 32;

    // ---- Q fragment (B-operand: col q = lq, elems d = 16t + 8*lh + j), x log2(e)
    constexpr float LOG2E = 1.44269504088896340736f;
    f16x8 qh[8];
    {
        const float* qs = Qp + (size_t)(q0 + lq) * DIM + 8 * lh;
#pragma unroll
        for (int t = 0; t < 8; ++t) {
            const float4 a = *(const float4*)(qs + 16 * t);
            const float4 b = *(const float4*)(qs + 16 * t + 4);
            float xs[8] = {a.x, a.y, a.z, a.w, b.x, b.y, b.z, b.w};
            f16x8 h;
#pragma unroll
            for (int e = 0; e < 8; ++e) h[e] = (_Float16)(xs[e] * LOG2E);
            qh[t] = h;
        }
    }

    // O^T accumulators: acc[dm][r] = O^T[d = 32*dm + (r&3)+8*(r>>2)+4*lh][q = lq]
    f32x16 acc[4];
#pragma unroll
    for (int a = 0; a < 4; ++a)
#pragma unroll
        for (int r = 0; r < 16; ++r) acc[a][r] = 0.0f;

    float mrow  = -3.0e38f;   // running (deferred) max, log2 units
    float mtrue = -3.0e38f;   // true running max, log2 units

    // staging maps (all static register indexing)
    const int ksr = tid >> 3, kc0 = (tid & 7) * 16;   // K: 8 threads/row, 16 floats
    const int vc  = tid & 31;                         // V: d cols {vc,+32,+64,+96}
    const int vk  = (tid >> 5) * 4;                   //    x 4 consecutive k rows
    const float* kb = Kp + (size_t)ksr * DIM + kc0;
    const float* vb = Vp + (size_t)vk * DIM + vc;

    float4 kreg[4];
    float  vreg[4][4];   // [d-col j][k-row r]

    auto stage = [&](int b) {
#pragma unroll
        for (int g = 0; g < 2; ++g) {
            float xs[8] = {kreg[2*g].x, kreg[2*g].y, kreg[2*g].z, kreg[2*g].w,
                           kreg[2*g+1].x, kreg[2*g+1].y, kreg[2*g+1].z, kreg[2*g+1].w};
            f16x8 h;
#pragma unroll
            for (int e = 0; e < 8; ++e) h[e] = (_Float16)xs[e];
            *(f16x8*)((char*)&Ksh[b][0] + (ksr * KSTR + kc0 + 8 * g) * 2) = h;
        }
#pragma unroll
        for (int j = 0; j < 4; ++j) {
            const int d = vc + 32 * j;
            f16x4 tv = {(_Float16)vreg[j][0], (_Float16)vreg[j][1],
                        (_Float16)vreg[j][2], (_Float16)vreg[j][3]};
            *(f16x4*)((char*)&Vt[b][0] + (d * VSTR + vk) * 2) = tv;
        }
    };
    auto loadT = [&](int t) {
        const float* ks_ = kb + (size_t)t * KVBLK * DIM;
        const float* vs_ = vb + (size_t)t * KVBLK * DIM;
#pragma unroll
        for (int u = 0; u < 4; ++u) kreg[u] = *(const float4*)(ks_ + u * 4);
#pragma unroll
        for (int j = 0; j < 4; ++j)
#pragma unroll
            for (int r = 0; r < 4; ++r) vreg[j][r] = vs_[(size_t)r * DIM + 32 * j];
    };

    // prologue: tile 0 staged; tile 1 in regs
    loadT(0);
    stage(0);
    loadT(1);

    for (int kt = 0; kt < nkt; ++kt) {
        const int cur = kt & 1;
        __syncthreads();   // buf[cur] writes visible; buf[cur^1] readers done

        if (kt + 1 < nkt) stage(cur ^ 1);    // tile kt+1 (regs loaded last iter)
        if (kt + 2 < nkt) loadT(kt + 2);     // issue tile kt+2 loads
        __builtin_amdgcn_sched_barrier(0);   // pin load issue here

        // ---- S^T = K Q^T, single pass, 2 interleaved accumulator chains
        const char* Kc = (const char*)&Ksh[cur][0];
        const char* Vc = (const char*)&Vt[cur][0];
        f32x16 s0, s1;
#pragma unroll
        for (int r = 0; r < 16; ++r) { s0[r] = 0.0f; s1[r] = 0.0f; }
        __builtin_amdgcn_s_setprio(1);
#pragma unroll
        for (int t = 0; t < 4; ++t) {
            f16x8 ka = *(const f16x8*)(Kc + (lq * KSTR + 32 * t + 8 * lh) * 2);
            f16x8 kc = *(const f16x8*)(Kc + (lq * KSTR + 32 * t + 16 + 8 * lh) * 2);
            s0 = MFMA32(ka, qh[2 * t], s0);
            s1 = MFMA32(kc, qh[2 * t + 1], s1);
        }
        __builtin_amdgcn_s_setprio(0);
        f32x16 st = s0 + s1;   // st[r] = S'^T[k = (r&3)+8*(r>>2)+4*lh][q = lq]

        // ---- speculative P with OLD mrow (no dependence on this tile's max)
        int pk[8];
#pragma unroll
        for (int i = 0; i < 8; ++i) {
            f16x2 e = {(_Float16)__builtin_exp2f(st[2 * i] - mrow),
                       (_Float16)__builtin_exp2f(st[2 * i + 1] - mrow)};
            pk[i] = __builtin_bit_cast(int, e);
        }

        // ---- row max (overlaps the exp2 block above in the scheduler)
        float tmax = fmaxf(fmaxf(fmaxf(st[0], st[1]), fmaxf(st[2], st[3])),
                           fmaxf(fmaxf(st[4], st[5]), fmaxf(st[6], st[7])));
        tmax = fmaxf(tmax, fmaxf(fmaxf(fmaxf(st[8], st[9]), fmaxf(st[10], st[11])),
                                 fmaxf(fmaxf(st[12], st[13]), fmaxf(st[14], st[15]))));
        tmax = fmaxf(tmax, __shfl_xor(tmax, 32));
        mtrue = fmaxf(mtrue, tmax);

        // ---- rare fixup: max grew by > THR -> rescale acc, recompute P exactly
        if (!__all(tmax - mrow <= 6.0f)) {
            const float mn  = fmaxf(mrow, tmax);
            const float scl = __builtin_exp2f(mrow - mn);
            mrow = mn;
#pragma unroll
            for (int a = 0; a < 4; ++a)
#pragma unroll
                for (int r = 0; r < 16; ++r) acc[a][r] *= scl;
#pragma unroll
            for (int i = 0; i < 8; ++i) {
                f16x2 e = {(_Float16)__builtin_exp2f(st[2 * i] - mn),
                           (_Float16)__builtin_exp2f(st[2 * i + 1] - mn)};
                pk[i] = __builtin_bit_cast(int, e);
            }
        }

        // ---- PV: O^T += V^T P^T (k = 16s + 8lh + j); permlane32_swap B-frags
#pragma unroll
        for (int s = 0; s < 2; ++s) {
            i32x2 w02 = __builtin_amdgcn_permlane32_swap(pk[4*s+0], pk[4*s+2], false, false);
            i32x2 w13 = __builtin_amdgcn_permlane32_swap(pk[4*s+1], pk[4*s+3], false, false);
            union { int i[4]; f16x8 v; } u;
            u.i[0] = w02[0]; u.i[1] = w13[0]; u.i[2] = w02[1]; u.i[3] = w13[1];
            const f16x8 pb = u.v;
            __builtin_amdgcn_s_setprio(1);
#pragma unroll
            for (int dm = 0; dm < 4; ++dm) {
                const int d = dm * 32 + lq;
                f16x8 va = *(const f16x8*)(Vc + (d * VSTR + 16 * s + 8 * lh) * 2);
                acc[dm] = MFMA32(va, pb, acc[dm]);
            }
            __builtin_amdgcn_s_setprio(0);
        }
    }

    // ---- correct to this launch's true row max (partial if split)
    const float fin = __builtin_exp2f(mrow - mtrue);
#pragma unroll
    for (int a = 0; a < 4; ++a)
#pragma unroll
        for (int r = 0; r < 16; ++r) acc[a][r] *= fin;

    // ---- store O partial; publish per-row max for the merge
    float* ob = Op + (size_t)(q0 + lq) * DIM + 4 * lh;
#pragma unroll
    for (int dm = 0; dm < 4; ++dm)
#pragma unroll
        for (int kp = 0; kp < 4; ++kp) {
            f32x4 v4 = {acc[dm][4*kp], acc[dm][4*kp+1], acc[dm][4*kp+2], acc[dm][4*kp+3]};
            *(f32x4*)(ob + dm * 32 + kp * 8) = v4;
        }
    if (split && lane < 32)
        Mbase[(size_t)khalf * (BH * SEQ) + (size_t)bh * SEQ + q0 + lq] = mtrue;
}

// O0 = O0*2^(m0-M) + O1*2^(m1-M), elementwise over [BH][SEQ][DIM] as float4
__global__ __launch_bounds__(256)
void fa_merge(float* __restrict__ O0, const float* __restrict__ O1,
              const float* __restrict__ M)
{
    const int idx = blockIdx.x * 256 + threadIdx.x;   // 0 .. BH*SEQ*DIM/4-1
    const int row = idx >> 5;                          // 32 float4 per 128-d row
    const float m0 = M[row];
    const float m1 = M[BH * SEQ + row];
    const float mm = fmaxf(m0, m1);
    const float s0 = __builtin_exp2f(m0 - mm);
    const float s1 = __builtin_exp2f(m1 - mm);
    float4 a = ((const float4*)O0)[idx];
    const float4 b = ((const float4*)O1)[idx];
    a.x = a.x * s0 + b.x * s1;
    a.y = a.y * s0 + b.y * s1;
    a.z = a.z * s0 + b.z * s1;
    a.w = a.w * s0 + b.w * s1;
    ((float4*)O0)[idx] = a;
}

extern "C" void kernel_launch(void* const* d_in, const int* in_sizes, int n_in,
                              void* d_out, int out_size, void* d_ws, size_t ws_size,
                              hipStream_t stream) {
    const float* q = (const float*)d_in[0];
    const float* k = (const float*)d_in[1];
    const float* v = (const float*)d_in[2];
    float* o = (float*)d_out;

    const size_t needO1 = (size_t)BH * SEQ * DIM * 4;   // 33,554,432 B
    const size_t needM  = (size_t)2 * BH * SEQ * 4;     //    524,288 B
    if (ws_size >= needO1 + needM) {
        float* O1 = (float*)d_ws;
        float* M  = (float*)((char*)d_ws + needO1);
        fa_fwd_kernel<<<dim3(2 * (SEQ / QBLK) * BH), dim3(256), 0, stream>>>(
            q, k, v, o, O1, M, 1);
        fa_merge<<<dim3(BH * SEQ * DIM / 4 / 256), dim3(256), 0, stream>>>(o, O1, M);
    } else {
        // fallback: single-kernel r14 path
        fa_fwd_kernel<<<dim3((SEQ / QBLK) * BH), dim3(256), 0, stream>>>(
            q, k, v, o, nullptr, nullptr, 0);
    }
}

// Round 17
// 115.400 us; speedup vs baseline: 2.2258x; 2.2258x over previous
//
#include <hip/hip_runtime.h>

typedef _Float16 f16x8  __attribute__((ext_vector_type(8)));
typedef _Float16 f16x4  __attribute__((ext_vector_type(4)));
typedef _Float16 f16x2  __attribute__((ext_vector_type(2)));
typedef float    f32x4  __attribute__((ext_vector_type(4)));
typedef float    f32x16 __attribute__((ext_vector_type(16)));
typedef int      i32x2  __attribute__((ext_vector_type(2)));

#define MFMA32(a, b, c) __builtin_amdgcn_mfma_f32_32x32x16_f16((a), (b), (c), 0, 0, 0)
// cvt_pkrtz returns __fp16x2; bit_cast to our _Float16-based f16x2
#define PKRTZ(a, b) __builtin_bit_cast(f16x2, __builtin_amdgcn_cvt_pkrtz((a), (b)))

static constexpr int SEQ   = 2048;
static constexpr int DIM   = 128;
static constexpr int QBLK  = 128;          // 4 waves x 32 q-rows
static constexpr int KVBLK = 32;           // kv rows per tile
static constexpr int NKT   = SEQ / KVBLK;  // 64 (even)
static constexpr int BH    = 2 * 16;
static constexpr int KSTR  = 136;          // K LDS row stride (f16), 272B padded
static constexpr int VSTR  = 40;           // Vt LDS row stride (f16), 80B padded

// o = exp(QK^T - rowmax) @ V  (unnormalized, fp32 in/out)
// r14 core, restructured: dual-bank staging registers (A=even tiles, B=odd),
// global-load issue pinned BEFORE sched_barrier, stage conversion AFTER it so
// the compiler interleaves stage VALU/ds_writes with the QK MFMA cluster.
// All f32->f16 conversion via v_cvt_pkrtz (packed, 1 op / 2 elems).
__global__ __launch_bounds__(256, 2)
void fa_fwd_kernel(const float* __restrict__ Qg, const float* __restrict__ Kg,
                   const float* __restrict__ Vg, float* __restrict__ Og)
{
    __shared__ __align__(16) _Float16 Ksh[2][KVBLK * KSTR];
    __shared__ __align__(16) _Float16 Vt[2][DIM * VSTR];

    const int tid  = threadIdx.x;
    const int wv   = tid >> 6;
    const int lane = tid & 63;
    const int lq   = lane & 31;   // q column (and K A-row) owned by this lane
    const int lh   = lane >> 5;   // half: 0/1

    // XCD swizzle: all 16 q-tiles of one bh -> one XCD (K/V L2-resident)
    const int bi = blockIdx.x;
    const int bh = (bi & 7) + 8 * (bi >> 7);
    const int qt = (bi >> 3) & 15;

    const size_t base = (size_t)bh * SEQ * DIM;
    const float* Qp = Qg + base;
    const float* Kp = Kg + base;
    const float* Vp = Vg + base;
    float*       Op = Og + base;

    const int q0 = qt * QBLK + wv * 32;

    // ---- Q fragment (B-operand: col q = lq, elems d = 16t + 8*lh + j), x log2(e)
    constexpr float LOG2E = 1.44269504088896340736f;
    f16x8 qh[8];
    {
        const float* qs = Qp + (size_t)(q0 + lq) * DIM + 8 * lh;
#pragma unroll
        for (int t = 0; t < 8; ++t) {
            const float4 a = *(const float4*)(qs + 16 * t);
            const float4 b = *(const float4*)(qs + 16 * t + 4);
            union { f16x2 h2[4]; f16x8 v; } u;
            u.h2[0] = PKRTZ(a.x * LOG2E, a.y * LOG2E);
            u.h2[1] = PKRTZ(a.z * LOG2E, a.w * LOG2E);
            u.h2[2] = PKRTZ(b.x * LOG2E, b.y * LOG2E);
            u.h2[3] = PKRTZ(b.z * LOG2E, b.w * LOG2E);
            qh[t] = u.v;
        }
    }

    // O^T accumulators: acc[dm][r] = O^T[d = 32*dm + (r&3)+8*(r>>2)+4*lh][q = lq]
    f32x16 acc[4];
#pragma unroll
    for (int a = 0; a < 4; ++a)
#pragma unroll
        for (int r = 0; r < 16; ++r) acc[a][r] = 0.0f;

    float mrow  = -3.0e38f;   // running (deferred) max, log2 units
    float mtrue = -3.0e38f;   // true running max, log2 units

    // staging maps (all static register indexing)
    const int ksr = tid >> 3, kc0 = (tid & 7) * 16;   // K: 8 threads/row, 16 floats
    const int vc  = tid & 31;                         // V: d cols {vc,+32,+64,+96}
    const int vk  = (tid >> 5) * 4;                   //    x 4 consecutive k rows
    const float* kb = Kp + (size_t)ksr * DIM + kc0;
    const float* vb = Vp + (size_t)vk * DIM + vc;

    // dual-bank staging registers: bank A = even tiles -> buf0, B = odd -> buf1
    float4 kregA[4], kregB[4];
    float  vregA[4][4], vregB[4][4];

#define LOAD_BANK(KR, VR, T)                                                \
    do {                                                                    \
        const float* ks_ = kb + (size_t)(T) * KVBLK * DIM;                  \
        const float* vs_ = vb + (size_t)(T) * KVBLK * DIM;                  \
        _Pragma("unroll")                                                   \
        for (int u_ = 0; u_ < 4; ++u_) KR[u_] = *(const float4*)(ks_ + u_ * 4); \
        _Pragma("unroll")                                                   \
        for (int j_ = 0; j_ < 4; ++j_)                                      \
            _Pragma("unroll")                                               \
            for (int r_ = 0; r_ < 4; ++r_)                                  \
                VR[j_][r_] = vs_[(size_t)r_ * DIM + 32 * j_];               \
    } while (0)

#define STAGE_BANK(KR, VR, B)                                               \
    do {                                                                    \
        _Pragma("unroll")                                                   \
        for (int g_ = 0; g_ < 2; ++g_) {                                    \
            union { f16x2 h2[4]; f16x8 v; } u_;                             \
            u_.h2[0] = PKRTZ(KR[2*g_].x, KR[2*g_].y);                       \
            u_.h2[1] = PKRTZ(KR[2*g_].z, KR[2*g_].w);                       \
            u_.h2[2] = PKRTZ(KR[2*g_+1].x, KR[2*g_+1].y);                   \
            u_.h2[3] = PKRTZ(KR[2*g_+1].z, KR[2*g_+1].w);                   \
            *(f16x8*)((char*)&Ksh[B][0] + (ksr * KSTR + kc0 + 8 * g_) * 2) = u_.v; \
        }                                                                   \
        _Pragma("unroll")                                                   \
        for (int j_ = 0; j_ < 4; ++j_) {                                    \
            union { f16x2 h2[2]; f16x4 v; } u_;                             \
            u_.h2[0] = PKRTZ(VR[j_][0], VR[j_][1]);                         \
            u_.h2[1] = PKRTZ(VR[j_][2], VR[j_][3]);                         \
            const int d_ = vc + 32 * j_;                                    \
            *(f16x4*)((char*)&Vt[B][0] + (d_ * VSTR + vk) * 2) = u_.v;      \
        }                                                                   \
    } while (0)

    // one full tile step: compute on buf CUR while staging the other bank
    auto computeTile = [&](int CUR) {
        const char* Kc = (const char*)&Ksh[CUR][0];
        const char* Vc = (const char*)&Vt[CUR][0];
        f32x16 s0, s1;
#pragma unroll
        for (int r = 0; r < 16; ++r) { s0[r] = 0.0f; s1[r] = 0.0f; }
        __builtin_amdgcn_s_setprio(1);
#pragma unroll
        for (int t = 0; t < 4; ++t) {
            f16x8 ka = *(const f16x8*)(Kc + (lq * KSTR + 32 * t + 8 * lh) * 2);
            f16x8 kc = *(const f16x8*)(Kc + (lq * KSTR + 32 * t + 16 + 8 * lh) * 2);
            s0 = MFMA32(ka, qh[2 * t], s0);
            s1 = MFMA32(kc, qh[2 * t + 1], s1);
        }
        __builtin_amdgcn_s_setprio(0);
        f32x16 st = s0 + s1;   // st[r] = S'^T[k = (r&3)+8*(r>>2)+4*lh][q = lq]

        // speculative P with OLD mrow (independent of this tile's max)
        int pk[8];
#pragma unroll
        for (int i = 0; i < 8; ++i)
            pk[i] = __builtin_bit_cast(int,
                PKRTZ(__builtin_exp2f(st[2 * i] - mrow),
                      __builtin_exp2f(st[2 * i + 1] - mrow)));

        // row max (overlaps the exp2 block in the scheduler)
        float tmax = fmaxf(fmaxf(fmaxf(st[0], st[1]), fmaxf(st[2], st[3])),
                           fmaxf(fmaxf(st[4], st[5]), fmaxf(st[6], st[7])));
        tmax = fmaxf(tmax, fmaxf(fmaxf(fmaxf(st[8], st[9]), fmaxf(st[10], st[11])),
                                 fmaxf(fmaxf(st[12], st[13]), fmaxf(st[14], st[15]))));
        tmax = fmaxf(tmax, __shfl_xor(tmax, 32));
        mtrue = fmaxf(mtrue, tmax);

        // rare fixup: max grew by > THR -> rescale acc, recompute P exactly
        if (!__all(tmax - mrow <= 6.0f)) {
            const float mn  = fmaxf(mrow, tmax);
            const float scl = __builtin_exp2f(mrow - mn);
            mrow = mn;
#pragma unroll
            for (int a = 0; a < 4; ++a)
#pragma unroll
                for (int r = 0; r < 16; ++r) acc[a][r] *= scl;
#pragma unroll
            for (int i = 0; i < 8; ++i)
                pk[i] = __builtin_bit_cast(int,
                    PKRTZ(__builtin_exp2f(st[2 * i] - mn),
                          __builtin_exp2f(st[2 * i + 1] - mn)));
        }

        // PV: O^T += V^T P^T (k = 16s + 8lh + j); permlane32_swap B-frags
#pragma unroll
        for (int s = 0; s < 2; ++s) {
            i32x2 w02 = __builtin_amdgcn_permlane32_swap(pk[4*s+0], pk[4*s+2], false, false);
            i32x2 w13 = __builtin_amdgcn_permlane32_swap(pk[4*s+1], pk[4*s+3], false, false);
            union { int i[4]; f16x8 v; } u;
            u.i[0] = w02[0]; u.i[1] = w13[0]; u.i[2] = w02[1]; u.i[3] = w13[1];
            const f16x8 pb = u.v;
            __builtin_amdgcn_s_setprio(1);
#pragma unroll
            for (int dm = 0; dm < 4; ++dm) {
                const int d = dm * 32 + lq;
                f16x8 va = *(const f16x8*)(Vc + (d * VSTR + 16 * s + 8 * lh) * 2);
                acc[dm] = MFMA32(va, pb, acc[dm]);
            }
            __builtin_amdgcn_s_setprio(0);
        }
    };

    // prologue: tile 0 -> A -> buf0; tile 1 -> B
    LOAD_BANK(kregA, vregA, 0);
    STAGE_BANK(kregA, vregA, 0);
    LOAD_BANK(kregB, vregB, 1);

    for (int kt = 0; kt < NKT; kt += 2) {
        // ---- phase A: compute buf0 (tile kt); stage B(tile kt+1)->buf1
        __syncthreads();
        if (kt + 2 < NKT) LOAD_BANK(kregA, vregA, kt + 2);   // issue loads first
        __builtin_amdgcn_sched_barrier(0);                   // pin loads above
        STAGE_BANK(kregB, vregB, 1);                         // interleaves w/ MFMA
        computeTile(0);

        // ---- phase B: compute buf1 (tile kt+1); stage A(tile kt+2)->buf0
        __syncthreads();
        if (kt + 3 < NKT) LOAD_BANK(kregB, vregB, kt + 3);
        __builtin_amdgcn_sched_barrier(0);
        if (kt + 2 < NKT) STAGE_BANK(kregA, vregA, 0);
        computeTile(1);
    }

    // ---- final correction to the true global row max (reference is unnormalized)
    const float fin = __builtin_exp2f(mrow - mtrue);
#pragma unroll
    for (int a = 0; a < 4; ++a)
#pragma unroll
        for (int r = 0; r < 16; ++r) acc[a][r] *= fin;

    // ---- store O: reg r of acc[dm] -> col d = 32*dm + 8*(r>>2) + 4*lh + (r&3)
    float* ob = Op + (size_t)(q0 + lq) * DIM + 4 * lh;
#pragma unroll
    for (int dm = 0; dm < 4; ++dm)
#pragma unroll
        for (int kp = 0; kp < 4; ++kp) {
            f32x4 v4 = {acc[dm][4*kp], acc[dm][4*kp+1], acc[dm][4*kp+2], acc[dm][4*kp+3]};
            *(f32x4*)(ob + dm * 32 + kp * 8) = v4;
        }
}

extern "C" void kernel_launch(void* const* d_in, const int* in_sizes, int n_in,
                              void* d_out, int out_size, void* d_ws, size_t ws_size,
                              hipStream_t stream) {
    const float* q = (const float*)d_in[0];
    const float* k = (const float*)d_in[1];
    const float* v = (const float*)d_in[2];
    float* o = (float*)d_out;
    dim3 grid((SEQ / QBLK) * BH);   // 512 blocks = 2/CU, XCD-swizzled in-kernel
    fa_fwd_kernel<<<grid, dim3(256), 0, stream>>>(q, k, v, o);
}